// Round 1
// baseline (291.967 us; speedup 1.0000x reference)
//
#include <hip/hip_runtime.h>
#include <hip/hip_bf16.h>

typedef __bf16 bf16_t;
typedef __attribute__((ext_vector_type(8))) __bf16 bf16x8;
typedef __attribute__((ext_vector_type(4))) float f32x4;

#define EPSF 1e-5f

// ===========================================================================
// S1 mega-kernel. Grid 640 x 256:
//   blocks [0,256):   gemm_ai  (hiddens @ W_ai[:, :2048].T) + folded ej GEMV
//                     (W_ai[:, 2048:] @ external) + fused attention-logit
//                     epilogue -> lp[jt*32 + n] partials (128 x 32)
//   blocks [256,512): gemm_fh  (hiddens @ W_fh.T) -> ws_fh[n][j]
//   blocks [512,640): gemv_fi  (W_fi @ input)     -> ws_fi[2048]
// MFMA 16x16x32 bf16, fp32 accumulate. 4 waves, each one K-quarter.
// A-frag: lane holds A[m=lane&15][k=quad*8+j]; B-frag: B[k][n=lane&15]
// D: lane L reg r -> row=(L>>4)*4+r, col=L&15
// K-loops unrolled (x2 ai / x4 fh) to raise outstanding-load count:
// latency-bound, not BW-bound (total stream 176MB vs 280us measured).
// ===========================================================================
__global__ __launch_bounds__(256) void s1_mega(
    const float* __restrict__ hiddens, const float* __restrict__ external,
    const float* __restrict__ input,
    const float* __restrict__ W_ai, const float* __restrict__ W_fh,
    const float* __restrict__ W_fi, const float* __restrict__ W_attn,
    float* __restrict__ lp, float* __restrict__ fh_out, float* __restrict__ fi_out)
{
    __shared__ float red[4][16][16];
    __shared__ float ejs[4][16];

    int b    = blockIdx.x;
    int tid  = threadIdx.x;
    int wave = tid >> 6;
    int lane = tid & 63;

    if (b < 512) {
        // ---------------- GEMM branch ----------------
        bool is_ai = (b < 256);
        int  bb    = is_ai ? b : b - 256;
        int  jt    = bb & 127;
        int  nt    = bb >> 7;
        int  l15   = lane & 15;
        int  quad  = lane >> 4;
        int  k0    = wave * 512;                  // K=2048, kper=512
        int  wstride = is_ai ? 4096 : 2048;
        const float* W = is_ai ? W_ai : W_fh;

        const float* ap = hiddens + (size_t)(nt * 16 + l15) * 2048 + quad * 8 + k0;
        const float* bp = W + (size_t)(jt * 16 + l15) * wstride + quad * 8 + k0;

        f32x4 acc = {0.f, 0.f, 0.f, 0.f};
        float ejacc = 0.f;

        if (is_ai) {
            const float* ep = bp + 2048;          // W_ai[row][2048 + ...]
            const float* xp = external + quad * 8 + k0;
            #pragma unroll 2
            for (int k = 0; k < 512; k += 32) {
                float4 a0 = *(const float4*)(ap + k);
                float4 a1 = *(const float4*)(ap + k + 4);
                float4 b0 = *(const float4*)(bp + k);
                float4 b1 = *(const float4*)(bp + k + 4);
                bf16x8 av, bv;
                av[0]=(bf16_t)a0.x; av[1]=(bf16_t)a0.y; av[2]=(bf16_t)a0.z; av[3]=(bf16_t)a0.w;
                av[4]=(bf16_t)a1.x; av[5]=(bf16_t)a1.y; av[6]=(bf16_t)a1.z; av[7]=(bf16_t)a1.w;
                bv[0]=(bf16_t)b0.x; bv[1]=(bf16_t)b0.y; bv[2]=(bf16_t)b0.z; bv[3]=(bf16_t)b0.w;
                bv[4]=(bf16_t)b1.x; bv[5]=(bf16_t)b1.y; bv[6]=(bf16_t)b1.z; bv[7]=(bf16_t)b1.w;
                acc = __builtin_amdgcn_mfma_f32_16x16x32_bf16(av, bv, acc, 0, 0, 0);
                float4 e0 = *(const float4*)(ep + k);
                float4 e1 = *(const float4*)(ep + k + 4);
                float4 x0 = *(const float4*)(xp + k);
                float4 x1 = *(const float4*)(xp + k + 4);
                ejacc += e0.x*x0.x + e0.y*x0.y + e0.z*x0.z + e0.w*x0.w
                       + e1.x*x1.x + e1.y*x1.y + e1.z*x1.z + e1.w*x1.w;
            }
            // reduce ej over the 4 quads sharing l15
            ejacc += __shfl_xor(ejacc, 16, 64);
            ejacc += __shfl_xor(ejacc, 32, 64);
            if (quad == 0) ejs[wave][l15] = ejacc;
        } else {
            #pragma unroll 4
            for (int k = 0; k < 512; k += 32) {
                float4 a0 = *(const float4*)(ap + k);
                float4 a1 = *(const float4*)(ap + k + 4);
                float4 b0 = *(const float4*)(bp + k);
                float4 b1 = *(const float4*)(bp + k + 4);
                bf16x8 av, bv;
                av[0]=(bf16_t)a0.x; av[1]=(bf16_t)a0.y; av[2]=(bf16_t)a0.z; av[3]=(bf16_t)a0.w;
                av[4]=(bf16_t)a1.x; av[5]=(bf16_t)a1.y; av[6]=(bf16_t)a1.z; av[7]=(bf16_t)a1.w;
                bv[0]=(bf16_t)b0.x; bv[1]=(bf16_t)b0.y; bv[2]=(bf16_t)b0.z; bv[3]=(bf16_t)b0.w;
                bv[4]=(bf16_t)b1.x; bv[5]=(bf16_t)b1.y; bv[6]=(bf16_t)b1.z; bv[7]=(bf16_t)b1.w;
                acc = __builtin_amdgcn_mfma_f32_16x16x32_bf16(av, bv, acc, 0, 0, 0);
            }
        }

        #pragma unroll
        for (int r = 0; r < 4; ++r) red[wave][quad * 4 + r][l15] = acc[r];
        __syncthreads();

        int row = tid >> 4, col = tid & 15;
        float s = red[0][row][col] + red[1][row][col] + red[2][row][col] + red[3][row][col];

        if (is_ai) {
            float ej = ejs[0][col] + ejs[1][col] + ejs[2][col] + ejs[3][col];
            float lg = tanhf(s + ej) * W_attn[jt * 16 + col];
            // reduce over the 16 cols within each row group (16 consecutive threads)
            lg += __shfl_xor(lg, 1, 64);
            lg += __shfl_xor(lg, 2, 64);
            lg += __shfl_xor(lg, 4, 64);
            lg += __shfl_xor(lg, 8, 64);
            if (col == 0) lp[jt * 32 + nt * 16 + row] = lg;
        } else {
            fh_out[(size_t)(nt * 16 + row) * 2048 + jt * 16 + col] = s;
        }
    } else {
        // ---------------- gemv_fi branch: 128 blocks, 16 rows each ----------
        int b2 = b - 512;
        #pragma unroll
        for (int r = 0; r < 4; ++r) {
            int row = b2 * 16 + wave * 4 + r;
            const float4* wp = (const float4*)(W_fi + (size_t)row * 2048) + lane;
            const float4* xp = (const float4*)input + lane;
            float acc2 = 0.f;
            #pragma unroll
            for (int k = 0; k < 512; k += 64) {
                float4 w = wp[k];
                float4 v = xp[k];
                acc2 += w.x*v.x + w.y*v.y + w.z*v.z + w.w*v.w;
            }
            #pragma unroll
            for (int off = 32; off; off >>= 1) acc2 += __shfl_down(acc2, off, 64);
            if (lane == 0) fi_out[row] = acc2;
        }
    }
}

// ===========================================================================
// S2 mega-kernel. Grid 40 x 256:
//   blocks [0,32):  per-child LN stats of f_lin[n] = fi + fh[n] -> frs[n]
//   blocks [32,40): reduce lp partials -> softmax over 32 (redundant per
//                   block) -> merged[h] slice
// ===========================================================================
__global__ __launch_bounds__(256) void s2_mega(
    const float* __restrict__ fi, const float* __restrict__ fh,
    const float* __restrict__ lp, const float* __restrict__ hiddens,
    float* __restrict__ frs, float* __restrict__ merged)
{
    __shared__ float s1[256], s2[256];
    int b = blockIdx.x, t = threadIdx.x;

    if (b < 32) {
        int n = b;
        float sum = 0.f, sq = 0.f;
        #pragma unroll
        for (int i = 0; i < 8; ++i) {
            int h = t * 8 + i;
            float v = fi[h] + fh[n * 2048 + h];
            sum += v; sq += v * v;
        }
        s1[t] = sum; s2[t] = sq;
        __syncthreads();
        for (int off = 128; off; off >>= 1) {
            if (t < off) { s1[t] += s1[t + off]; s2[t] += s2[t + off]; }
            __syncthreads();
        }
        if (t == 0) {
            const float inv = 1.f / 2048.f;
            float mean = s1[0] * inv;
            frs[n * 2]     = mean;
            frs[n * 2 + 1] = rsqrtf(s2[0] * inv - mean * mean + EPSF);
        }
    } else {
        // logits: sum 128 partials per n.  t -> n = t>>3, slice s = t&7 (16 each)
        __shared__ float lred[32][8];
        __shared__ float attnw[32];
        int n = t >> 3, sl = t & 7;
        float p = 0.f;
        #pragma unroll
        for (int m = 0; m < 16; ++m) p += lp[(sl * 16 + m) * 32 + n];
        lred[n][sl] = p;
        __syncthreads();
        if (sl == 0) {
            float lg = 0.f;
            #pragma unroll
            for (int m = 0; m < 8; ++m) lg += lred[n][m];
            lred[n][0] = lg;
        }
        __syncthreads();
        if (t < 32) {
            // softmax over 32 (each of the 32 threads redundantly scans)
            float mx = -1e30f;
            for (int m = 0; m < 32; ++m) mx = fmaxf(mx, lred[m][0]);
            float ssum = 0.f;
            for (int m = 0; m < 32; ++m) ssum += expf(lred[m][0] - mx);
            attnw[t] = expf(lred[t][0] - mx) / ssum;
        }
        __syncthreads();
        int h = (b - 32) * 256 + t;
        float acc = 0.f;
        #pragma unroll 8
        for (int n2 = 0; n2 < 32; ++n2) acc += attnw[n2] * hiddens[n2 * 2048 + h];
        merged[h] = acc;
    }
}

// ===========================================================================
// S3 mega-kernel. Grid 520 x 256:
//   blocks [0,512):   gemv  mm = W_merge @ merged   (4 rows / block)
//   blocks [512,520): fc[h] = sum_n sigmoid(LN_n(fi+fh)[h]*g+b) * cells[n][h]
// ===========================================================================
__global__ __launch_bounds__(256) void s3_mega(
    const float* __restrict__ W_merge, const float* __restrict__ merged,
    const float* __restrict__ fi, const float* __restrict__ fh,
    const float* __restrict__ frs, const float* __restrict__ gf,
    const float* __restrict__ bf_, const float* __restrict__ cells,
    float* __restrict__ mm, float* __restrict__ fc)
{
    int b = blockIdx.x, t = threadIdx.x;
    if (b < 512) {
        int row  = b * 4 + (t >> 6);
        int lane = t & 63;
        const float4* wp = (const float4*)(W_merge + (size_t)row * 2048) + lane;
        const float4* xp = (const float4*)merged + lane;
        float acc = 0.f;
        #pragma unroll
        for (int k = 0; k < 512; k += 64) {
            float4 w = wp[k];
            float4 v = xp[k];
            acc += w.x*v.x + w.y*v.y + w.z*v.z + w.w*v.w;
        }
        #pragma unroll
        for (int off = 32; off; off >>= 1) acc += __shfl_down(acc, off, 64);
        if (lane == 0) mm[row] = acc;
    } else {
        int h = (b - 512) * 256 + t;
        float g = gf[h], bb = bf_[h], f_i = fi[h];
        float acc = 0.f;
        for (int n = 0; n < 32; ++n) {
            float v = (f_i + fh[n * 2048 + h] - frs[n * 2]) * frs[n * 2 + 1] * g + bb;
            float f = 1.f / (1.f + expf(-v));
            acc += f * cells[n * 2048 + h];
        }
        fc[h] = acc;
    }
}

// ===========================================================================
// S4: gemv iou = W_iou @ xcat, with xcat = [input ; tanh(LN(mm)*g+b)]
// built redundantly per block into LDS.
// Grid 1536 x 256, ONE row per wave (4 rows / block):
//   1536 blocks / 256 CUs = exactly 6 blocks/CU -> perfect balance
//   (vs 384 blocks = 1.5/CU: half the CUs ran 2 blocks -> 33% tail),
//   24 waves/CU resident, 16 fully-unrolled float4 loads in flight/wave.
// ===========================================================================
__global__ __launch_bounds__(256) void s4_iou(
    const float* __restrict__ W_iou, const float* __restrict__ mm,
    const float* __restrict__ input, const float* __restrict__ g,
    const float* __restrict__ bvec, float* __restrict__ iou)
{
    __shared__ float xcat[4096];
    __shared__ float s1[256], s2[256];
    int b = blockIdx.x, t = threadIdx.x;

    float v[8]; float sum = 0.f, sq = 0.f;
    #pragma unroll
    for (int i = 0; i < 8; ++i) {
        v[i] = mm[t * 8 + i]; sum += v[i]; sq += v[i] * v[i];
    }
    s1[t] = sum; s2[t] = sq;
    __syncthreads();
    for (int off = 128; off; off >>= 1) {
        if (t < off) { s1[t] += s1[t + off]; s2[t] += s2[t + off]; }
        __syncthreads();
    }
    const float inv = 1.f / 2048.f;
    float mean = s1[0] * inv;
    float r = rsqrtf(s2[0] * inv - mean * mean + EPSF);
    #pragma unroll
    for (int i = 0; i < 8; ++i) {
        int h = t * 8 + i;
        xcat[h]        = input[h];
        xcat[2048 + h] = tanhf((v[i] - mean) * r * g[h] + bvec[h]);
    }
    __syncthreads();

    int wave = t >> 6, lane = t & 63;
    int row = b * 4 + wave;
    const float4* wp = (const float4*)(W_iou + (size_t)row * 4096) + lane;
    const float4* xp = (const float4*)xcat + lane;
    float acc = 0.f;
    #pragma unroll
    for (int k = 0; k < 1024; k += 64) {
        float4 w = wp[k];
        float4 x = xp[k];
        acc += w.x*x.x + w.y*x.y + w.z*x.z + w.w*x.w;
    }
    #pragma unroll
    for (int off = 32; off; off >>= 1) acc += __shfl_down(acc, off, 64);
    if (lane == 0) iou[row] = acc;
}

// ===========================================================================
// S5: fused tail — i/o/u LN stats + gates, v = i*u + fc, LN(v), fp32 out.
// One block of 256.
// ===========================================================================
__global__ __launch_bounds__(256) void s5_tail(
    const float* __restrict__ iou, const float* __restrict__ fc,
    const float* __restrict__ gi, const float* __restrict__ bi,
    const float* __restrict__ go, const float* __restrict__ bo,
    const float* __restrict__ gu, const float* __restrict__ bu,
    const float* __restrict__ gc, const float* __restrict__ bc,
    float* __restrict__ out)
{
    __shared__ float sA[6][256];
    int t = threadIdx.x;
    float vi[8], vo[8], vu[8];
    float si = 0, qi = 0, so = 0, qo = 0, su = 0, qu = 0;
    #pragma unroll
    for (int i = 0; i < 8; ++i) {
        int h = t * 8 + i;
        vi[i] = iou[h]; vo[i] = iou[2048 + h]; vu[i] = iou[4096 + h];
        si += vi[i]; qi += vi[i] * vi[i];
        so += vo[i]; qo += vo[i] * vo[i];
        su += vu[i]; qu += vu[i] * vu[i];
    }
    sA[0][t] = si; sA[1][t] = qi; sA[2][t] = so;
    sA[3][t] = qo; sA[4][t] = su; sA[5][t] = qu;
    __syncthreads();
    for (int off = 128; off; off >>= 1) {
        if (t < off) {
            #pragma unroll
            for (int c = 0; c < 6; ++c) sA[c][t] += sA[c][t + off];
        }
        __syncthreads();
    }
    const float inv = 1.f / 2048.f;
    float mi = sA[0][0] * inv, ri = rsqrtf(sA[1][0] * inv - mi * mi + EPSF);
    float mo = sA[2][0] * inv, ro = rsqrtf(sA[3][0] * inv - mo * mo + EPSF);
    float mu = sA[4][0] * inv, ru = rsqrtf(sA[5][0] * inv - mu * mu + EPSF);
    __syncthreads();

    float o_[8], v_[8];
    float sv = 0, qv = 0;
    #pragma unroll
    for (int i = 0; i < 8; ++i) {
        int h = t * 8 + i;
        float ivl = 1.f / (1.f + expf(-((vi[i] - mi) * ri * gi[h] + bi[h])));
        o_[i]     = 1.f / (1.f + expf(-((vo[i] - mo) * ro * go[h] + bo[h])));
        float uvl = tanhf((vu[i] - mu) * ru * gu[h] + bu[h]);
        v_[i] = ivl * uvl + fc[h];
        sv += v_[i]; qv += v_[i] * v_[i];
    }
    sA[0][t] = sv; sA[1][t] = qv;
    __syncthreads();
    for (int off = 128; off; off >>= 1) {
        if (t < off) { sA[0][t] += sA[0][t + off]; sA[1][t] += sA[1][t + off]; }
        __syncthreads();
    }
    float mc = sA[0][0] * inv, rc = rsqrtf(sA[1][0] * inv - mc * mc + EPSF);
    #pragma unroll
    for (int i = 0; i < 8; ++i) {
        int h = t * 8 + i;
        float nc = (v_[i] - mc) * rc * gc[h] + bc[h];
        float nh = o_[i] * tanhf(nc);
        out[h]        = nh;   // new_h
        out[2048 + h] = nc;   // new_cell
    }
}

// ---------------------------------------------------------------------------
extern "C" void kernel_launch(void* const* d_in, const int* in_sizes, int n_in,
                              void* d_out, int out_size, void* d_ws, size_t ws_size,
                              hipStream_t stream)
{
    const float* input    = (const float*)d_in[0];   // [2048]
    const float* hiddens  = (const float*)d_in[1];   // [32,2048]
    const float* cells    = (const float*)d_in[2];   // [32,2048]
    const float* external = (const float*)d_in[3];   // [2048]
    const float* W_ai     = (const float*)d_in[4];   // [2048,4096]
    const float* W_attn   = (const float*)d_in[5];   // [1,2048]
    const float* W_merge  = (const float*)d_in[6];   // [2048,2048]
    const float* W_iou    = (const float*)d_in[7];   // [6144,4096]
    const float* W_fi     = (const float*)d_in[8];   // [2048,2048]
    const float* W_fh     = (const float*)d_in[9];   // [2048,2048]
    const float* g_merge  = (const float*)d_in[10];
    const float* b_merge  = (const float*)d_in[11];
    const float* g_f      = (const float*)d_in[12];
    const float* b_f      = (const float*)d_in[13];
    const float* g_i      = (const float*)d_in[14];
    const float* b_i      = (const float*)d_in[15];
    const float* g_o      = (const float*)d_in[16];
    const float* b_o      = (const float*)d_in[17];
    const float* g_u      = (const float*)d_in[18];
    const float* b_u      = (const float*)d_in[19];
    const float* g_c      = (const float*)d_in[20];
    const float* b_c      = (const float*)d_in[21];

    float* ws = (float*)d_ws;
    float* ws_fh     = ws;              // 32*2048 = 65536
    float* ws_fi     = ws + 65536;      // 2048
    float* ws_lp     = ws + 67584;      // 128*32 = 4096
    float* ws_frs    = ws + 71680;      // 64
    float* ws_merged = ws + 71744;      // 2048
    float* ws_mm     = ws + 73792;      // 2048
    float* ws_fc     = ws + 75840;      // 2048
    float* ws_iou    = ws + 77888;      // 6144
    float* out = (float*)d_out;

    s1_mega<<<640, 256, 0, stream>>>(hiddens, external, input,
                                     W_ai, W_fh, W_fi, W_attn,
                                     ws_lp, ws_fh, ws_fi);
    s2_mega<<<40, 256, 0, stream>>>(ws_fi, ws_fh, ws_lp, hiddens,
                                    ws_frs, ws_merged);
    s3_mega<<<520, 256, 0, stream>>>(W_merge, ws_merged, ws_fi, ws_fh,
                                     ws_frs, g_f, b_f, cells, ws_mm, ws_fc);
    s4_iou<<<1536, 256, 0, stream>>>(W_iou, ws_mm, input, g_merge, b_merge, ws_iou);
    s5_tail<<<1, 256, 0, stream>>>(ws_iou, ws_fc, g_i, b_i, g_o, b_o,
                                   g_u, b_u, g_c, b_c, out);
}

// Round 2
// 281.371 us; speedup vs baseline: 1.0377x; 1.0377x over previous
//
#include <hip/hip_runtime.h>
#include <hip/hip_bf16.h>

typedef __bf16 bf16_t;
typedef __attribute__((ext_vector_type(8))) __bf16 bf16x8;
typedef __attribute__((ext_vector_type(4))) float f32x4;

#define EPSF 1e-5f

// ===========================================================================
// S1 mega-kernel. Grid 512 x 256 (exactly 2 blocks/CU):
//   blocks [0,128):   gemm_ai: DUAL-nt — one W_ai tile read feeds BOTH child
//                     halves (acc0: children 0-15, acc1: 16-31). Folded ej
//                     GEMV + fused attention-logit epilogue -> lp partials.
//   blocks [128,256): gemm_fh: dual-nt, same dedupe -> ws_fh[n][j]
//   blocks [256,512): gemv_fi: 4-row blocks first (pair with heavy ai
//                     blocks), 12-row blocks second (pair with light fh).
// MFMA 16x16x32 bf16, fp32 accumulate. 4 waves, each one K-quarter.
// Dedupe halves W_ai/W_fh traffic (was read once per nt: 96MB -> 48MB).
// ===========================================================================
__global__ __launch_bounds__(256) void s1_mega(
    const float* __restrict__ hiddens, const float* __restrict__ external,
    const float* __restrict__ input,
    const float* __restrict__ W_ai, const float* __restrict__ W_fh,
    const float* __restrict__ W_fi, const float* __restrict__ W_attn,
    float* __restrict__ lp, float* __restrict__ fh_out, float* __restrict__ fi_out)
{
    __shared__ float red[4][2][16][16];
    __shared__ float ejs[4][16];

    int b    = blockIdx.x;
    int tid  = threadIdx.x;
    int wave = tid >> 6;
    int lane = tid & 63;

    if (b < 256) {
        // ---------------- GEMM branch (dual-nt) ----------------
        bool is_ai = (b < 128);
        int  jt    = is_ai ? b : b - 128;
        int  l15   = lane & 15;
        int  quad  = lane >> 4;
        int  k0    = wave * 512;                  // K=2048, kper=512
        int  wstride = is_ai ? 4096 : 2048;
        const float* W = is_ai ? W_ai : W_fh;

        const float* a0p = hiddens + (size_t)l15 * 2048 + quad * 8 + k0;        // children 0..15
        const float* a1p = hiddens + (size_t)(16 + l15) * 2048 + quad * 8 + k0; // children 16..31
        const float* bp  = W + (size_t)(jt * 16 + l15) * wstride + quad * 8 + k0;

        f32x4 acc0 = {0.f, 0.f, 0.f, 0.f};
        f32x4 acc1 = {0.f, 0.f, 0.f, 0.f};
        float ejacc = 0.f;

        if (is_ai) {
            const float* ep = bp + 2048;          // W_ai[row][2048 + ...]
            const float* xp = external + quad * 8 + k0;
            #pragma unroll 2
            for (int k = 0; k < 512; k += 32) {
                float4 p0 = *(const float4*)(a0p + k);
                float4 p1 = *(const float4*)(a0p + k + 4);
                float4 q0 = *(const float4*)(a1p + k);
                float4 q1 = *(const float4*)(a1p + k + 4);
                float4 b0 = *(const float4*)(bp + k);
                float4 b1 = *(const float4*)(bp + k + 4);
                float4 e0 = *(const float4*)(ep + k);
                float4 e1 = *(const float4*)(ep + k + 4);
                float4 x0 = *(const float4*)(xp + k);
                float4 x1 = *(const float4*)(xp + k + 4);
                bf16x8 av0, av1, bv;
                av0[0]=(bf16_t)p0.x; av0[1]=(bf16_t)p0.y; av0[2]=(bf16_t)p0.z; av0[3]=(bf16_t)p0.w;
                av0[4]=(bf16_t)p1.x; av0[5]=(bf16_t)p1.y; av0[6]=(bf16_t)p1.z; av0[7]=(bf16_t)p1.w;
                av1[0]=(bf16_t)q0.x; av1[1]=(bf16_t)q0.y; av1[2]=(bf16_t)q0.z; av1[3]=(bf16_t)q0.w;
                av1[4]=(bf16_t)q1.x; av1[5]=(bf16_t)q1.y; av1[6]=(bf16_t)q1.z; av1[7]=(bf16_t)q1.w;
                bv[0]=(bf16_t)b0.x; bv[1]=(bf16_t)b0.y; bv[2]=(bf16_t)b0.z; bv[3]=(bf16_t)b0.w;
                bv[4]=(bf16_t)b1.x; bv[5]=(bf16_t)b1.y; bv[6]=(bf16_t)b1.z; bv[7]=(bf16_t)b1.w;
                acc0 = __builtin_amdgcn_mfma_f32_16x16x32_bf16(av0, bv, acc0, 0, 0, 0);
                acc1 = __builtin_amdgcn_mfma_f32_16x16x32_bf16(av1, bv, acc1, 0, 0, 0);
                ejacc += e0.x*x0.x + e0.y*x0.y + e0.z*x0.z + e0.w*x0.w
                       + e1.x*x1.x + e1.y*x1.y + e1.z*x1.z + e1.w*x1.w;
            }
            // reduce ej over the 4 quads sharing l15
            ejacc += __shfl_xor(ejacc, 16, 64);
            ejacc += __shfl_xor(ejacc, 32, 64);
            if (quad == 0) ejs[wave][l15] = ejacc;
        } else {
            #pragma unroll 2
            for (int k = 0; k < 512; k += 32) {
                float4 p0 = *(const float4*)(a0p + k);
                float4 p1 = *(const float4*)(a0p + k + 4);
                float4 q0 = *(const float4*)(a1p + k);
                float4 q1 = *(const float4*)(a1p + k + 4);
                float4 b0 = *(const float4*)(bp + k);
                float4 b1 = *(const float4*)(bp + k + 4);
                bf16x8 av0, av1, bv;
                av0[0]=(bf16_t)p0.x; av0[1]=(bf16_t)p0.y; av0[2]=(bf16_t)p0.z; av0[3]=(bf16_t)p0.w;
                av0[4]=(bf16_t)p1.x; av0[5]=(bf16_t)p1.y; av0[6]=(bf16_t)p1.z; av0[7]=(bf16_t)p1.w;
                av1[0]=(bf16_t)q0.x; av1[1]=(bf16_t)q0.y; av1[2]=(bf16_t)q0.z; av1[3]=(bf16_t)q0.w;
                av1[4]=(bf16_t)q1.x; av1[5]=(bf16_t)q1.y; av1[6]=(bf16_t)q1.z; av1[7]=(bf16_t)q1.w;
                bv[0]=(bf16_t)b0.x; bv[1]=(bf16_t)b0.y; bv[2]=(bf16_t)b0.z; bv[3]=(bf16_t)b0.w;
                bv[4]=(bf16_t)b1.x; bv[5]=(bf16_t)b1.y; bv[6]=(bf16_t)b1.z; bv[7]=(bf16_t)b1.w;
                acc0 = __builtin_amdgcn_mfma_f32_16x16x32_bf16(av0, bv, acc0, 0, 0, 0);
                acc1 = __builtin_amdgcn_mfma_f32_16x16x32_bf16(av1, bv, acc1, 0, 0, 0);
            }
        }

        #pragma unroll
        for (int r = 0; r < 4; ++r) {
            red[wave][0][quad * 4 + r][l15] = acc0[r];
            red[wave][1][quad * 4 + r][l15] = acc1[r];
        }
        __syncthreads();

        int row = tid >> 4, col = tid & 15;
        #pragma unroll
        for (int nt = 0; nt < 2; ++nt) {
            float s = red[0][nt][row][col] + red[1][nt][row][col]
                    + red[2][nt][row][col] + red[3][nt][row][col];
            if (is_ai) {
                float ej = ejs[0][col] + ejs[1][col] + ejs[2][col] + ejs[3][col];
                float lg = tanhf(s + ej) * W_attn[jt * 16 + col];
                // reduce over the 16 cols within each row group
                lg += __shfl_xor(lg, 1, 64);
                lg += __shfl_xor(lg, 2, 64);
                lg += __shfl_xor(lg, 4, 64);
                lg += __shfl_xor(lg, 8, 64);
                if (col == 0) lp[jt * 32 + nt * 16 + row] = lg;
            } else {
                fh_out[(size_t)(nt * 16 + row) * 2048 + jt * 16 + col] = s;
            }
        }
    } else {
        // ---------------- gemv_fi branch: 256 blocks ----------
        // blocks [256,384): 4 rows each (rows 0..511)   — pair with heavy ai
        // blocks [384,512): 12 rows each (rows 512..2047) — pair with light fh
        int nb = b - 256;
        int base, nr;
        if (nb < 128) { base = nb * 4;              nr = 1; }
        else          { base = 512 + (nb - 128) * 12; nr = 3; }
        for (int r = 0; r < nr; ++r) {
            int row = base + wave * nr + r;
            const float4* wp = (const float4*)(W_fi + (size_t)row * 2048) + lane;
            const float4* xp = (const float4*)input + lane;
            float acc2 = 0.f;
            #pragma unroll
            for (int k = 0; k < 512; k += 64) {
                float4 w = wp[k];
                float4 v = xp[k];
                acc2 += w.x*v.x + w.y*v.y + w.z*v.z + w.w*v.w;
            }
            #pragma unroll
            for (int off = 32; off; off >>= 1) acc2 += __shfl_down(acc2, off, 64);
            if (lane == 0) fi_out[row] = acc2;
        }
    }
}

// ===========================================================================
// S2 mega-kernel. Grid 40 x 256:
//   blocks [0,32):  per-child LN stats of f_lin[n] = fi + fh[n] -> frs[n]
//   blocks [32,40): reduce lp partials -> softmax over 32 (redundant per
//                   block) -> merged[h] slice
// ===========================================================================
__global__ __launch_bounds__(256) void s2_mega(
    const float* __restrict__ fi, const float* __restrict__ fh,
    const float* __restrict__ lp, const float* __restrict__ hiddens,
    float* __restrict__ frs, float* __restrict__ merged)
{
    __shared__ float s1[256], s2[256];
    int b = blockIdx.x, t = threadIdx.x;

    if (b < 32) {
        int n = b;
        float sum = 0.f, sq = 0.f;
        #pragma unroll
        for (int i = 0; i < 8; ++i) {
            int h = t * 8 + i;
            float v = fi[h] + fh[n * 2048 + h];
            sum += v; sq += v * v;
        }
        s1[t] = sum; s2[t] = sq;
        __syncthreads();
        for (int off = 128; off; off >>= 1) {
            if (t < off) { s1[t] += s1[t + off]; s2[t] += s2[t + off]; }
            __syncthreads();
        }
        if (t == 0) {
            const float inv = 1.f / 2048.f;
            float mean = s1[0] * inv;
            frs[n * 2]     = mean;
            frs[n * 2 + 1] = rsqrtf(s2[0] * inv - mean * mean + EPSF);
        }
    } else {
        // logits: sum 128 partials per n.  t -> n = t>>3, slice s = t&7 (16 each)
        __shared__ float lred[32][8];
        __shared__ float attnw[32];
        int n = t >> 3, sl = t & 7;
        float p = 0.f;
        #pragma unroll
        for (int m = 0; m < 16; ++m) p += lp[(sl * 16 + m) * 32 + n];
        lred[n][sl] = p;
        __syncthreads();
        if (sl == 0) {
            float lg = 0.f;
            #pragma unroll
            for (int m = 0; m < 8; ++m) lg += lred[n][m];
            lred[n][0] = lg;
        }
        __syncthreads();
        if (t < 32) {
            float mx = -1e30f;
            for (int m = 0; m < 32; ++m) mx = fmaxf(mx, lred[m][0]);
            float ssum = 0.f;
            for (int m = 0; m < 32; ++m) ssum += expf(lred[m][0] - mx);
            attnw[t] = expf(lred[t][0] - mx) / ssum;
        }
        __syncthreads();
        int h = (b - 32) * 256 + t;
        float acc = 0.f;
        #pragma unroll 8
        for (int n2 = 0; n2 < 32; ++n2) acc += attnw[n2] * hiddens[n2 * 2048 + h];
        merged[h] = acc;
    }
}

// ===========================================================================
// S3 mega-kernel. Grid 520 x 256:
//   blocks [0,512):   gemv  mm = W_merge @ merged   (4 rows / block)
//   blocks [512,520): fc[h] = sum_n sigmoid(LN_n(fi+fh)[h]*g+b) * cells[n][h]
// ===========================================================================
__global__ __launch_bounds__(256) void s3_mega(
    const float* __restrict__ W_merge, const float* __restrict__ merged,
    const float* __restrict__ fi, const float* __restrict__ fh,
    const float* __restrict__ frs, const float* __restrict__ gf,
    const float* __restrict__ bf_, const float* __restrict__ cells,
    float* __restrict__ mm, float* __restrict__ fc)
{
    int b = blockIdx.x, t = threadIdx.x;
    if (b < 512) {
        int row  = b * 4 + (t >> 6);
        int lane = t & 63;
        const float4* wp = (const float4*)(W_merge + (size_t)row * 2048) + lane;
        const float4* xp = (const float4*)merged + lane;
        float acc = 0.f;
        #pragma unroll
        for (int k = 0; k < 512; k += 64) {
            float4 w = wp[k];
            float4 v = xp[k];
            acc += w.x*v.x + w.y*v.y + w.z*v.z + w.w*v.w;
        }
        #pragma unroll
        for (int off = 32; off; off >>= 1) acc += __shfl_down(acc, off, 64);
        if (lane == 0) mm[row] = acc;
    } else {
        int h = (b - 512) * 256 + t;
        float g = gf[h], bb = bf_[h], f_i = fi[h];
        float acc = 0.f;
        for (int n = 0; n < 32; ++n) {
            float v = (f_i + fh[n * 2048 + h] - frs[n * 2]) * frs[n * 2 + 1] * g + bb;
            float f = 1.f / (1.f + expf(-v));
            acc += f * cells[n * 2048 + h];
        }
        fc[h] = acc;
    }
}

// ===========================================================================
// S4: gemv iou = W_iou @ xcat, xcat = [input ; tanh(LN(mm)*g+b)].
// BARRIER-FREE: each wave independently
//   (1) loads mm (8 x float4, L2-hot), shfl-reduces LN stats (no LDS),
//   (2) builds the full 4096-wide x in 16 float4 REGISTERS (lane k-slice),
//   (3) streams 2 rows of W_iou (16KB each) and dot-products from regs.
// No __syncthreads, no LDS -> zero bank conflicts, ~100% streaming duty.
// Grid 768 x 256 = exactly 3 blocks/CU; launch_bounds(256,3) keeps VGPR
// <= 170 so all 3 co-reside (12 waves/CU).
// ===========================================================================
__global__ __launch_bounds__(256, 3) void s4_iou(
    const float* __restrict__ W_iou, const float* __restrict__ mm,
    const float* __restrict__ input, const float* __restrict__ g,
    const float* __restrict__ bvec, float* __restrict__ iou)
{
    int b = blockIdx.x, t = threadIdx.x;
    int wave = t >> 6, lane = t & 63;

    const float4* mm4 = (const float4*)mm;
    const float4* in4 = (const float4*)input;
    const float4* g4  = (const float4*)g;
    const float4* b4  = (const float4*)bvec;

    float4 mv[8];
    #pragma unroll
    for (int k = 0; k < 8; ++k) mv[k] = mm4[lane + 64 * k];
    float sum = 0.f, sq = 0.f;
    #pragma unroll
    for (int k = 0; k < 8; ++k) {
        sum += mv[k].x + mv[k].y + mv[k].z + mv[k].w;
        sq  += mv[k].x*mv[k].x + mv[k].y*mv[k].y + mv[k].z*mv[k].z + mv[k].w*mv[k].w;
    }
    #pragma unroll
    for (int off = 1; off < 64; off <<= 1) {
        sum += __shfl_xor(sum, off, 64);
        sq  += __shfl_xor(sq,  off, 64);
    }
    const float inv = 1.f / 2048.f;
    float mean = sum * inv;
    float r = rsqrtf(sq * inv - mean * mean + EPSF);

    float4 xr[16];
    #pragma unroll
    for (int k = 0; k < 8; ++k) xr[k] = in4[lane + 64 * k];
    #pragma unroll
    for (int k = 0; k < 8; ++k) {
        float4 gv = g4[lane + 64 * k];
        float4 bv = b4[lane + 64 * k];
        xr[8 + k].x = tanhf((mv[k].x - mean) * r * gv.x + bv.x);
        xr[8 + k].y = tanhf((mv[k].y - mean) * r * gv.y + bv.y);
        xr[8 + k].z = tanhf((mv[k].z - mean) * r * gv.z + bv.z);
        xr[8 + k].w = tanhf((mv[k].w - mean) * r * gv.w + bv.w);
    }

    int row0 = (b * 4 + wave) * 2;
    for (int rr = 0; rr < 2; ++rr) {
        const float4* wp = (const float4*)(W_iou + (size_t)(row0 + rr) * 4096);
        float acc = 0.f;
        #pragma unroll
        for (int k = 0; k < 16; ++k) {
            float4 w = wp[lane + 64 * k];
            acc += w.x*xr[k].x + w.y*xr[k].y + w.z*xr[k].z + w.w*xr[k].w;
        }
        #pragma unroll
        for (int off = 32; off; off >>= 1) acc += __shfl_down(acc, off, 64);
        if (lane == 0) iou[row0 + rr] = acc;
    }
}

// ===========================================================================
// S5: fused tail — i/o/u LN stats + gates, v = i*u + fc, LN(v), fp32 out.
// One block of 256.
// ===========================================================================
__global__ __launch_bounds__(256) void s5_tail(
    const float* __restrict__ iou, const float* __restrict__ fc,
    const float* __restrict__ gi, const float* __restrict__ bi,
    const float* __restrict__ go, const float* __restrict__ bo,
    const float* __restrict__ gu, const float* __restrict__ bu,
    const float* __restrict__ gc, const float* __restrict__ bc,
    float* __restrict__ out)
{
    __shared__ float sA[6][256];
    int t = threadIdx.x;
    float vi[8], vo[8], vu[8];
    float si = 0, qi = 0, so = 0, qo = 0, su = 0, qu = 0;
    #pragma unroll
    for (int i = 0; i < 8; ++i) {
        int h = t * 8 + i;
        vi[i] = iou[h]; vo[i] = iou[2048 + h]; vu[i] = iou[4096 + h];
        si += vi[i]; qi += vi[i] * vi[i];
        so += vo[i]; qo += vo[i] * vo[i];
        su += vu[i]; qu += vu[i] * vu[i];
    }
    sA[0][t] = si; sA[1][t] = qi; sA[2][t] = so;
    sA[3][t] = qo; sA[4][t] = su; sA[5][t] = qu;
    __syncthreads();
    for (int off = 128; off; off >>= 1) {
        if (t < off) {
            #pragma unroll
            for (int c = 0; c < 6; ++c) sA[c][t] += sA[c][t + off];
        }
        __syncthreads();
    }
    const float inv = 1.f / 2048.f;
    float mi = sA[0][0] * inv, ri = rsqrtf(sA[1][0] * inv - mi * mi + EPSF);
    float mo = sA[2][0] * inv, ro = rsqrtf(sA[3][0] * inv - mo * mo + EPSF);
    float mu = sA[4][0] * inv, ru = rsqrtf(sA[5][0] * inv - mu * mu + EPSF);
    __syncthreads();

    float o_[8], v_[8];
    float sv = 0, qv = 0;
    #pragma unroll
    for (int i = 0; i < 8; ++i) {
        int h = t * 8 + i;
        float ivl = 1.f / (1.f + expf(-((vi[i] - mi) * ri * gi[h] + bi[h])));
        o_[i]     = 1.f / (1.f + expf(-((vo[i] - mo) * ro * go[h] + bo[h])));
        float uvl = tanhf((vu[i] - mu) * ru * gu[h] + bu[h]);
        v_[i] = ivl * uvl + fc[h];
        sv += v_[i]; qv += v_[i] * v_[i];
    }
    sA[0][t] = sv; sA[1][t] = qv;
    __syncthreads();
    for (int off = 128; off; off >>= 1) {
        if (t < off) { sA[0][t] += sA[0][t + off]; sA[1][t] += sA[1][t + off]; }
        __syncthreads();
    }
    float mc = sA[0][0] * inv, rc = rsqrtf(sA[1][0] * inv - mc * mc + EPSF);
    #pragma unroll
    for (int i = 0; i < 8; ++i) {
        int h = t * 8 + i;
        float nc = (v_[i] - mc) * rc * gc[h] + bc[h];
        float nh = o_[i] * tanhf(nc);
        out[h]        = nh;   // new_h
        out[2048 + h] = nc;   // new_cell
    }
}

// ---------------------------------------------------------------------------
extern "C" void kernel_launch(void* const* d_in, const int* in_sizes, int n_in,
                              void* d_out, int out_size, void* d_ws, size_t ws_size,
                              hipStream_t stream)
{
    const float* input    = (const float*)d_in[0];   // [2048]
    const float* hiddens  = (const float*)d_in[1];   // [32,2048]
    const float* cells    = (const float*)d_in[2];   // [32,2048]
    const float* external = (const float*)d_in[3];   // [2048]
    const float* W_ai     = (const float*)d_in[4];   // [2048,4096]
    const float* W_attn   = (const float*)d_in[5];   // [1,2048]
    const float* W_merge  = (const float*)d_in[6];   // [2048,2048]
    const float* W_iou    = (const float*)d_in[7];   // [6144,4096]
    const float* W_fi     = (const float*)d_in[8];   // [2048,2048]
    const float* W_fh     = (const float*)d_in[9];   // [2048,2048]
    const float* g_merge  = (const float*)d_in[10];
    const float* b_merge  = (const float*)d_in[11];
    const float* g_f      = (const float*)d_in[12];
    const float* b_f      = (const float*)d_in[13];
    const float* g_i      = (const float*)d_in[14];
    const float* b_i      = (const float*)d_in[15];
    const float* g_o      = (const float*)d_in[16];
    const float* b_o      = (const float*)d_in[17];
    const float* g_u      = (const float*)d_in[18];
    const float* b_u      = (const float*)d_in[19];
    const float* g_c      = (const float*)d_in[20];
    const float* b_c      = (const float*)d_in[21];

    float* ws = (float*)d_ws;
    float* ws_fh     = ws;              // 32*2048 = 65536
    float* ws_fi     = ws + 65536;      // 2048
    float* ws_lp     = ws + 67584;      // 128*32 = 4096
    float* ws_frs    = ws + 71680;      // 64
    float* ws_merged = ws + 71744;      // 2048
    float* ws_mm     = ws + 73792;      // 2048
    float* ws_fc     = ws + 75840;      // 2048
    float* ws_iou    = ws + 77888;      // 6144
    float* out = (float*)d_out;

    s1_mega<<<512, 256, 0, stream>>>(hiddens, external, input,
                                     W_ai, W_fh, W_fi, W_attn,
                                     ws_lp, ws_fh, ws_fi);
    s2_mega<<<40, 256, 0, stream>>>(ws_fi, ws_fh, ws_lp, hiddens,
                                    ws_frs, ws_merged);
    s3_mega<<<520, 256, 0, stream>>>(W_merge, ws_merged, ws_fi, ws_fh,
                                     ws_frs, g_f, b_f, cells, ws_mm, ws_fc);
    s4_iou<<<768, 256, 0, stream>>>(W_iou, ws_mm, input, g_merge, b_merge, ws_iou);
    s5_tail<<<1, 256, 0, stream>>>(ws_iou, ws_fc, g_i, b_i, g_o, b_o,
                                   g_u, b_u, g_c, b_c, out);
}